// Round 3
// baseline (229.034 us; speedup 1.0000x reference)
//
#include <hip/hip_runtime.h>

#define NI 6144
#define NJ 6144
#define M_ROWS 1024
#define K_COLS 256
#define ROWS_PER_BLOCK 8
#define EMD_BLOCKS (NI / ROWS_PER_BLOCK)   // 768 = exactly 3 blocks/CU (48 KB LDS)

// ---------------------------------------------------------------------------
// Fused kernel:
//   blocks [0, M_ROWS)              : simplex projection of row blockIdx.x
//   blocks [M_ROWS, M_ROWS+EMD_BLKS): EMD partial sums (8 x-rows per block)
// Simplex blocks are placed FIRST so they dispatch/retire quickly and the
// long-running HBM-bound EMD blocks backfill, overlapping the two phases.
// ---------------------------------------------------------------------------
__global__ __launch_bounds__(256) void fused_kernel(
    const float* __restrict__ y_i, const float* __restrict__ y_j,
    const float* __restrict__ x, const float* __restrict__ f,
    float* __restrict__ partial, float* __restrict__ out) {
  // 48 KB shared, aliased by both branches.
  __shared__ float4 smem[NJ / 2];
  const int tid = threadIdx.x;
  const int lane = tid & 63;
  const int wid = tid >> 6;

  if (blockIdx.x >= M_ROWS) {
    // =================== EMD partial block ===================
    const int b = blockIdx.x - M_ROWS;
    // De-interleaved y_j: yj0[j] then yj1[j], each NJ/4 float4s (24 KB).
    float4* yj0v = smem;
    float4* yj1v = smem + NJ / 4;
    {
      const float4* yj4 = (const float4*)y_j;   // (y0,y1,y0,y1) = 2 js
      float* s0 = (float*)yj0v;
      float* s1 = (float*)yj1v;
      for (int t = tid; t < NJ / 2; t += 256) {
        const float4 v = yj4[t];
        s0[2 * t]     = v.x;  s1[2 * t]     = v.y;
        s0[2 * t + 1] = v.z;  s1[2 * t + 1] = v.w;
      }
    }
    __syncthreads();

    const int row0 = b * ROWS_PER_BLOCK;
    float yi0[ROWS_PER_BLOCK], yi1[ROWS_PER_BLOCK];
#pragma unroll
    for (int r = 0; r < ROWS_PER_BLOCK; ++r) {
      yi0[r] = y_i[2 * (row0 + r)];
      yi1[r] = y_i[2 * (row0 + r) + 1];
    }

    float acc = 0.0f;
#pragma unroll
    for (int t = 0; t < NJ / 4 / 256; ++t) {     // 6 iterations
      const int idx = tid + t * 256;             // float4 group of 4 js
      const float4 ya = yj0v[idx];               // shared across all 8 rows
      const float4 yb = yj1v[idx];
#pragma unroll
      for (int r = 0; r < ROWS_PER_BLOCK; ++r) {
        const float4 xv =
            ((const float4*)(x + (size_t)(row0 + r) * NJ))[idx];  // coalesced
        acc += xv.x * (fabsf(yi0[r] - ya.x) + fabsf(yi1[r] - yb.x));
        acc += xv.y * (fabsf(yi0[r] - ya.y) + fabsf(yi1[r] - yb.y));
        acc += xv.z * (fabsf(yi0[r] - ya.z) + fabsf(yi1[r] - yb.z));
        acc += xv.w * (fabsf(yi0[r] - ya.w) + fabsf(yi1[r] - yb.w));
      }
    }

    for (int off = 32; off > 0; off >>= 1) acc += __shfl_down(acc, off, 64);
    float* wsum = (float*)smem;  // safe: all LDS reads above are complete
    __syncthreads();             // (protect aliasing of smem)
    if (lane == 0) wsum[wid] = acc;
    __syncthreads();
    if (tid == 0) partial[b] = wsum[0] + wsum[1] + wsum[2] + wsum[3];
    return;
  }

  // =================== simplex block ===================
  const int row = blockIdx.x;
  float* s = (float*)smem;          // 256 floats
  float* wpre = s + K_COLS;         // 4 floats
  const float fv = f[row * K_COLS + tid];

  // Bitonic sort DESCENDING over 256 values held one-per-thread in x.
  float xv = fv;
#pragma unroll
  for (int k = 2; k <= 64; k <<= 1) {
#pragma unroll
    for (int j = k >> 1; j > 0; j >>= 1) {       // all j < 64: in-wave
      const float pv = __shfl_xor(xv, j, 64);
      const bool up = ((tid & k) == 0);
      const bool lower = ((tid & j) == 0);
      xv = (up == lower) ? fmaxf(xv, pv) : fminf(xv, pv);
    }
  }
  // k = 128: j=64 via LDS, then j<64 via shfl
  {
    s[tid] = xv; __syncthreads();
    const float pv = s[tid ^ 64]; __syncthreads();
    const bool up = ((tid & 128) == 0);
    xv = (up == ((tid & 64) == 0)) ? fmaxf(xv, pv) : fminf(xv, pv);
#pragma unroll
    for (int j = 32; j > 0; j >>= 1) {
      const float pv2 = __shfl_xor(xv, j, 64);
      xv = (up == ((tid & j) == 0)) ? fmaxf(xv, pv2) : fminf(xv, pv2);
    }
  }
  // k = 256: final full descending merge
  {
    s[tid] = xv; __syncthreads();
    float pv = s[tid ^ 128]; __syncthreads();
    xv = ((tid & 128) == 0) ? fmaxf(xv, pv) : fminf(xv, pv);
    s[tid] = xv; __syncthreads();
    pv = s[tid ^ 64]; __syncthreads();
    xv = ((tid & 64) == 0) ? fmaxf(xv, pv) : fminf(xv, pv);
#pragma unroll
    for (int j = 32; j > 0; j >>= 1) {
      const float pv2 = __shfl_xor(xv, j, 64);
      xv = ((tid & j) == 0) ? fmaxf(xv, pv2) : fminf(xv, pv2);
    }
  }

  const float u = xv;  // u[tid] = tid-th largest

  // Inclusive prefix sum across 256 threads.
  float cs = u;
#pragma unroll
  for (int off = 1; off < 64; off <<= 1) {
    const float t = __shfl_up(cs, off, 64);
    if (lane >= off) cs += t;
  }
  if (lane == 63) wpre[wid] = cs;
  __syncthreads();
  float base = 0.0f;
#pragma unroll
  for (int w = 0; w < 4; ++w)
    if (w < wid) base += wpre[w];
  cs += base;

  const float vt = (cs - 1.0f) / (float)(tid + 1);
  __syncthreads();                               // s reuse
  s[tid] = vt;
  const int cnt = __syncthreads_count(u > vt);   // rho + 1 (is a barrier)
  const float w = s[cnt - 1];

  out[1 + row * K_COLS + tid] = fmaxf(fv - w, 0.0f);
}

// ---------------------------------------------------------------------------
// Finisher: reduce the 768 EMD partials -> out[0]  (1 block)
// ---------------------------------------------------------------------------
__global__ __launch_bounds__(256) void finish_kernel(
    const float* __restrict__ partial, float* __restrict__ out) {
  const int tid = threadIdx.x;
  float acc = partial[tid] + partial[tid + 256] + partial[tid + 512];
  for (int off = 32; off > 0; off >>= 1) acc += __shfl_down(acc, off, 64);
  __shared__ float wsum[4];
  if ((tid & 63) == 0) wsum[tid >> 6] = acc;
  __syncthreads();
  if (tid == 0)
    out[0] = (wsum[0] + wsum[1] + wsum[2] + wsum[3]) * 1.25f;  // 1/R = 1/0.8
}

// ---------------------------------------------------------------------------
extern "C" void kernel_launch(void* const* d_in, const int* in_sizes, int n_in,
                              void* d_out, int out_size, void* d_ws,
                              size_t ws_size, hipStream_t stream) {
  const float* y_i = (const float*)d_in[0];
  const float* y_j = (const float*)d_in[1];
  const float* x   = (const float*)d_in[2];
  const float* f   = (const float*)d_in[3];
  float* out = (float*)d_out;
  float* partial = (float*)d_ws;  // 768 floats

  fused_kernel<<<M_ROWS + EMD_BLOCKS, 256, 0, stream>>>(y_i, y_j, x, f,
                                                        partial, out);
  finish_kernel<<<1, 256, 0, stream>>>(partial, out);
}